// Round 1
// baseline (1085.053 us; speedup 1.0000x reference)
//
#include <hip/hip_runtime.h>

// Problem constants
// V=50000, E=64, B=64, T=1024, F=128, H=128, WIN=3, PAD=1
// K = WIN*E = 192 fused-conv reduction dim; G = 2*3H = 768 projection outputs

typedef __attribute__((ext_vector_type(8))) unsigned short ushort8;

__device__ __forceinline__ unsigned short f2bf(float f) {
  unsigned int u = __float_as_uint(f);
  u += 0x7fffu + ((u >> 16) & 1u);   // round-to-nearest-even
  return (unsigned short)(u >> 16);
}
__device__ __forceinline__ float bf2f(unsigned short us) {
  return __uint_as_float(((unsigned int)us) << 16);
}
#define DOT4(a, b) ((a).x*(b).x + (a).y*(b).y + (a).z*(b).z + (a).w*(b).w)

// ---------------------------------------------------------------------------
// K0: fuse conv weights into projection: CW[g][k] = sum_f Wih[g][f]*conv_w[f][k]
//     (k = w*64+e), xbias[g] = b_ih[g] + sum_f Wih[g][f]*conv_b[f].
//     g<384 -> forward (w_ih_f); g>=384 -> backward (w_ih_b).
__global__ void k0_fuse(const float* __restrict__ conv_w, const float* __restrict__ conv_b,
                        const float* __restrict__ w_ih_f, const float* __restrict__ b_ih_f,
                        const float* __restrict__ w_ih_b, const float* __restrict__ b_ih_b,
                        float* __restrict__ CW, float* __restrict__ xbias) {
  int flat = blockIdx.x * 256 + threadIdx.x;
  if (flat >= 768 * 192) return;
  int g = flat / 192, k = flat % 192;
  const float* wih = (g < 384) ? w_ih_f : w_ih_b;
  int gg = (g < 384) ? g : g - 384;
  float acc = 0.f;
  for (int f = 0; f < 128; ++f) acc += wih[gg * 128 + f] * conv_w[f * 192 + k];
  CW[g * 192 + k] = acc;
  if (k == 0) {
    const float* bih = (g < 384) ? b_ih_f : b_ih_b;
    float bb = bih[gg];
    for (int f = 0; f < 128; ++f) bb += wih[gg * 128 + f] * conv_b[f];
    xbias[g] = bb;
  }
}

// ---------------------------------------------------------------------------
// K1: xp[b][t][g] = xbias[g] + sum_k A[t][k]*CW[g][k], A[t][k] = emb[ipts[b][t-1+w]][e]
//     Block tile: 128 t x 128 g, K=192 fully in LDS. Thread tile 8t x 8g.
//     t per-thread interleaved (t = ti + 16r) so xs reads are 2-way-max conflicts.
__global__ __launch_bounds__(256) void k1_gemm(const int* __restrict__ ipts,
                                               const float* __restrict__ emb,
                                               const float* __restrict__ CW,
                                               const float* __restrict__ xbias,
                                               unsigned short* __restrict__ xp) {
  __shared__ float xs[130][68];    // 130 emb rows (halo +-1), pad 68 for banks/alignment
  __shared__ float wsm[128][196];  // 128 g rows of CW chunk, pad 196
  const int bid = blockIdx.x;
  const int gb = bid % 6;         // 6 g-chunks of 128 (768 total)
  const int tb = bid / 6;         // 512 = 64 b * 8 t-tiles
  const int b = tb >> 3;
  const int t0 = (tb & 7) << 7;
  const int g0 = gb << 7;
  const int tid = threadIdx.x;

  // stage A rows (emb gather with zero halo)
  for (int idx = tid; idx < 130 * 16; idx += 256) {
    int row = idx >> 4, c = idx & 15;
    int t = t0 - 1 + row;
    float4 v = make_float4(0.f, 0.f, 0.f, 0.f);
    if (t >= 0 && t < 1024) {
      int tok = ipts[b * 1024 + t];
      v = *reinterpret_cast<const float4*>(emb + (size_t)tok * 64 + c * 4);
    }
    *reinterpret_cast<float4*>(&xs[row][c * 4]) = v;
  }
  // stage W chunk
  for (int idx = tid; idx < 128 * 48; idx += 256) {
    int g = idx / 48, c = idx % 48;
    *reinterpret_cast<float4*>(&wsm[g][c * 4]) =
        *reinterpret_cast<const float4*>(CW + (size_t)(g0 + g) * 192 + c * 4);
  }
  __syncthreads();

  const int ti = tid & 15;   // t-group: rows ti + 16r
  const int gi = tid >> 4;   // g-group: cols gi*8 + s
  float acc[8][8];
#pragma unroll
  for (int r = 0; r < 8; ++r)
#pragma unroll
    for (int s = 0; s < 8; ++s) acc[r][s] = 0.f;

#pragma unroll 2
  for (int kk = 0; kk < 48; ++kk) {
    const int xrow = kk >> 4;          // w offset (k = w*64 + e)
    const int xcol = (kk & 15) * 4;    // e offset
    float4 av[8], wv[8];
#pragma unroll
    for (int r = 0; r < 8; ++r)
      av[r] = *reinterpret_cast<const float4*>(&xs[ti + 16 * r + xrow][xcol]);
#pragma unroll
    for (int s = 0; s < 8; ++s)
      wv[s] = *reinterpret_cast<const float4*>(&wsm[gi * 8 + s][kk * 4]);
#pragma unroll
    for (int r = 0; r < 8; ++r)
#pragma unroll
      for (int s = 0; s < 8; ++s) {
        acc[r][s] += av[r].x * wv[s].x;
        acc[r][s] += av[r].y * wv[s].y;
        acc[r][s] += av[r].z * wv[s].z;
        acc[r][s] += av[r].w * wv[s].w;
      }
  }

  float bias[8];
#pragma unroll
  for (int s = 0; s < 8; ++s) bias[s] = xbias[g0 + gi * 8 + s];
#pragma unroll
  for (int r = 0; r < 8; ++r) {
    int t = t0 + ti + 16 * r;
    ushort8 pk;
#pragma unroll
    for (int s = 0; s < 8; ++s) pk[s] = f2bf(acc[r][s] + bias[s]);
    *reinterpret_cast<ushort8*>(xp + (size_t)(b * 1024 + t) * 768 + g0 + gi * 8) = pk;
  }
}

// ---------------------------------------------------------------------------
// K2: GRU scan. One block per (batch, direction); 512 threads.
//     Per step: gh = h @ w_hh^T with w_hh in VGPRs (thread = 2 j x 3 gates x 16 k),
//     h broadcast from LDS, partials reduced through padded LDS, gate combine on
//     tid<128, masked-mean accumulated in registers. Loop runs exactly len steps.
__global__ __launch_bounds__(512) void k2_scan(
    const int* __restrict__ seqlen, const float* __restrict__ hidden,
    const float* __restrict__ w_hh_f, const float* __restrict__ b_hh_f,
    const float* __restrict__ w_hh_b, const float* __restrict__ b_hh_b,
    const unsigned short* __restrict__ xp, float* __restrict__ mot) {
  __shared__ float hpad[160];          // h[j] at j + (j>>4)*4 (bank-spread float4 reads)
  __shared__ float pbuf[8][3][132];    // [kq][gate][j], pad 132
  const int tid = threadIdx.x;
  const int b = blockIdx.x & 63;
  const int dir = blockIdx.x >> 6;
  const int q = tid & 7;               // k-chunk: k in [q*16, q*16+16)
  const int j0 = (tid >> 3) * 2;       // owns j0, j0+1
  const float* whh = dir ? w_hh_b : w_hh_f;
  const float* bhh = dir ? b_hh_b : b_hh_f;

  float4 wv[3][2][4];
#pragma unroll
  for (int g = 0; g < 3; ++g)
#pragma unroll
    for (int jf = 0; jf < 2; ++jf) {
      const float* rp = whh + (size_t)(g * 128 + j0 + jf) * 128 + q * 16;
#pragma unroll
      for (int c = 0; c < 4; ++c)
        wv[g][jf][c] = *reinterpret_cast<const float4*>(rp + c * 4);
    }

  const int len = seqlen[b];
  float h_reg = 0.f, acc = 0.f, bh0 = 0.f, bh1 = 0.f, bh2 = 0.f;
  if (tid < 128) {
    h_reg = hidden[(dir * 64 + b) * 128 + tid];
    hpad[tid + (tid >> 4) * 4] = h_reg;
    bh0 = bhh[tid]; bh1 = bhh[128 + tid]; bh2 = bhh[256 + tid];
  }
  const unsigned short* xpu = xp + (size_t)b * (1024 * 768) + dir * 384;
  unsigned short xr_r = 0, xz_r = 0, xn_r = 0;
  if (tid < 128) {  // prologue prefetch t=0
    int tr0 = dir ? (len - 1) : 0;
    const unsigned short* pp = xpu + (size_t)tr0 * 768 + tid;
    xr_r = pp[0]; xz_r = pp[128]; xn_r = pp[256];
  }
  __syncthreads();

  for (int t = 0; t < len; ++t) {
    float p00 = 0.f, p01 = 0.f, p10 = 0.f, p11 = 0.f, p20 = 0.f, p21 = 0.f;
#pragma unroll
    for (int c = 0; c < 4; ++c) {
      float4 h4 = *reinterpret_cast<const float4*>(&hpad[q * 20 + c * 4]);
      p00 += DOT4(wv[0][0][c], h4);
      p01 += DOT4(wv[0][1][c], h4);
      p10 += DOT4(wv[1][0][c], h4);
      p11 += DOT4(wv[1][1][c], h4);
      p20 += DOT4(wv[2][0][c], h4);
      p21 += DOT4(wv[2][1][c], h4);
    }
    *reinterpret_cast<float2*>(&pbuf[q][0][j0]) = make_float2(p00, p01);
    *reinterpret_cast<float2*>(&pbuf[q][1][j0]) = make_float2(p10, p11);
    *reinterpret_cast<float2*>(&pbuf[q][2][j0]) = make_float2(p20, p21);
    __syncthreads();
    if (tid < 128) {
      float hr = 0.f, hz = 0.f, hn = 0.f;
#pragma unroll
      for (int qq = 0; qq < 8; ++qq) {
        hr += pbuf[qq][0][tid];
        hz += pbuf[qq][1][tid];
        hn += pbuf[qq][2][tid];
      }
      float xr = bf2f(xr_r), xz = bf2f(xz_r), xn = bf2f(xn_r);
      float r = 1.f / (1.f + __expf(-(xr + hr + bh0)));
      float z = 1.f / (1.f + __expf(-(xz + hz + bh1)));
      float narg = xn + r * (hn + bh2);
      float e2 = __expf(2.f * narg);
      float n = (e2 - 1.f) / (e2 + 1.f);
      float hnew = (1.f - z) * n + z * h_reg;
      acc += hnew;
      h_reg = hnew;
      hpad[tid + (tid >> 4) * 4] = hnew;
      if (t + 1 < len) {  // prefetch next step's xp (in flight across 2 barriers + FMA)
        int trn = dir ? (len - 2 - t) : (t + 1);
        const unsigned short* pp = xpu + (size_t)trn * 768 + tid;
        xr_r = pp[0]; xz_r = pp[128]; xn_r = pp[256];
      }
    }
    __syncthreads();
  }
  if (tid < 128) mot[b * 256 + dir * 128 + tid] = acc / (float)len;
}

// ---------------------------------------------------------------------------
// K3: out[b] = sigmoid(dot(mot[b], lin_w) + lin_b)
__global__ void k3_final(const float* __restrict__ mot, const float* __restrict__ lin_w,
                         const float* __restrict__ lin_b, float* __restrict__ out) {
  int tid = threadIdx.x;
  int b = tid >> 2, part = tid & 3;
  float s = 0.f;
  for (int i = 0; i < 64; ++i) s += mot[b * 256 + part * 64 + i] * lin_w[part * 64 + i];
  s += __shfl_xor(s, 1);
  s += __shfl_xor(s, 2);
  if (part == 0) out[b] = 1.f / (1.f + __expf(-(s + lin_b[0])));
}

// ---------------------------------------------------------------------------
extern "C" void kernel_launch(void* const* d_in, const int* in_sizes, int n_in,
                              void* d_out, int out_size, void* d_ws, size_t ws_size,
                              hipStream_t stream) {
  const int*   ipts    = (const int*)d_in[0];
  const int*   seqlen  = (const int*)d_in[1];
  const float* hidden  = (const float*)d_in[2];
  const float* emb     = (const float*)d_in[3];
  const float* conv_w  = (const float*)d_in[4];
  const float* conv_b  = (const float*)d_in[5];
  const float* w_ih_f  = (const float*)d_in[6];
  const float* w_hh_f  = (const float*)d_in[7];
  const float* b_ih_f  = (const float*)d_in[8];
  const float* b_hh_f  = (const float*)d_in[9];
  const float* w_ih_b  = (const float*)d_in[10];
  const float* w_hh_b  = (const float*)d_in[11];
  const float* b_ih_b  = (const float*)d_in[12];
  const float* b_hh_b  = (const float*)d_in[13];
  const float* lin_w   = (const float*)d_in[14];
  const float* lin_b   = (const float*)d_in[15];

  char* ws = (char*)d_ws;
  float* CW    = (float*)(ws);                 // 768*192*4 = 589,824 B
  float* xbias = (float*)(ws + 589824);        // 768*4
  float* mot   = (float*)(ws + 655360);        // 64*256*4 = 65,536 B
  unsigned short* xp = (unsigned short*)(ws + 1048576);  // 64*1024*768*2 = 100,663,296 B
  float* out = (float*)d_out;

  hipLaunchKernelGGL(k0_fuse, dim3(576), dim3(256), 0, stream,
                     conv_w, conv_b, w_ih_f, b_ih_f, w_ih_b, b_ih_b, CW, xbias);
  hipLaunchKernelGGL(k1_gemm, dim3(3072), dim3(256), 0, stream,
                     ipts, emb, CW, xbias, xp);
  hipLaunchKernelGGL(k2_scan, dim3(128), dim3(512), 0, stream,
                     seqlen, hidden, w_hh_f, b_hh_f, w_hh_b, b_hh_b, xp, mot);
  hipLaunchKernelGGL(k3_final, dim3(1), dim3(256), 0, stream, mot, lin_w, lin_b, out);
}

// Round 2
// 669.101 us; speedup vs baseline: 1.6217x; 1.6217x over previous
//
#include <hip/hip_runtime.h>

// V=50000, E=64, B=64, T=1024, F=128, H=128, WIN=3, PAD=1
// K = WIN*E = 192 fused reduction dim; G = 2*3H = 768 projection outputs

typedef __attribute__((ext_vector_type(8))) unsigned short ushort8;
typedef __attribute__((ext_vector_type(8))) short bf16x8;   // MFMA bf16 frag (guide §3)
typedef __attribute__((ext_vector_type(4))) float f32x4;
typedef _Float16 f16x2 __attribute__((ext_vector_type(2)));

__device__ __forceinline__ unsigned short f2bf(float f) {
  unsigned int u = __float_as_uint(f);
  u += 0x7fffu + ((u >> 16) & 1u);   // RNE
  return (unsigned short)(u >> 16);
}
__device__ __forceinline__ float bf2f(unsigned short us) {
  return __uint_as_float(((unsigned int)us) << 16);
}
__device__ __forceinline__ f16x2 us2h2(unsigned short a, unsigned short b) {
  unsigned int u = (unsigned int)a | ((unsigned int)b << 16);
  return __builtin_bit_cast(f16x2, u);
}
__device__ __forceinline__ unsigned short f2h_bits(float f) {
  _Float16 h = (_Float16)f;
  return __builtin_bit_cast(unsigned short, h);
}

#if __has_builtin(__builtin_amdgcn_fdot2)
#define FDOT2(a, b, c) __builtin_amdgcn_fdot2((a), (b), (c), false)
#else
#define FDOT2(a, b, c) ((float)(a).x * (float)(b).x + (float)(a).y * (float)(b).y + (c))
#endif

// ---------------------------------------------------------------------------
// K0: CWb[g][k] = bf16( sum_f Wih[g][f]*conv_w[f][k] ), xbias[g] = b_ih[g]+Wih[g]·conv_b
__global__ void k0_fuse(const float* __restrict__ conv_w, const float* __restrict__ conv_b,
                        const float* __restrict__ w_ih_f, const float* __restrict__ b_ih_f,
                        const float* __restrict__ w_ih_b, const float* __restrict__ b_ih_b,
                        unsigned short* __restrict__ CWb, float* __restrict__ xbias) {
  int flat = blockIdx.x * 256 + threadIdx.x;
  if (flat >= 768 * 192) return;
  int g = flat / 192, k = flat % 192;
  const float* wih = (g < 384) ? w_ih_f : w_ih_b;
  int gg = (g < 384) ? g : g - 384;
  float acc = 0.f;
  for (int f = 0; f < 128; ++f) acc += wih[gg * 128 + f] * conv_w[f * 192 + k];
  CWb[g * 192 + k] = f2bf(acc);
  if (k == 0) {
    const float* bih = (g < 384) ? b_ih_f : b_ih_b;
    float bb = bih[gg];
    for (int f = 0; f < 128; ++f) bb += wih[gg * 128 + f] * conv_b[f];
    xbias[g] = bb;
  }
}

// ---------------------------------------------------------------------------
// K1: xp[b][t][g] = bf16( xbias[g] + sum_k A[t][k]*CW[g][k] ) via MFMA bf16.
//     Block = 128t x 128g, K=192. 4 waves in 2x2, wave tile 64x64 (4x4 frags).
//     A[t][k=w*64+e] = emb[ipts[t-1+w]][e] -> xs rows with +-1 halo.
__global__ __launch_bounds__(256) void k1_gemm(const int* __restrict__ ipts,
                                               const float* __restrict__ emb,
                                               const unsigned short* __restrict__ CWb,
                                               const float* __restrict__ xbias,
                                               unsigned short* __restrict__ xp) {
  __shared__ __align__(16) unsigned short xs[130][72];    // bf16 emb rows, stride 144B
  __shared__ __align__(16) unsigned short wsb[128][200];  // bf16 CW chunk, stride 400B
  const int bid = blockIdx.x;
  const int gb = bid % 6, tb = bid / 6;
  const int b = tb >> 3, t0 = (tb & 7) << 7, g0 = gb << 7;
  const int tid = threadIdx.x;

  for (int c = tid; c < 130 * 16; c += 256) {   // stage A (gather + f32->bf16)
    int row = c >> 4, cc = c & 15;
    int t = t0 - 1 + row;
    float4 v = make_float4(0.f, 0.f, 0.f, 0.f);
    if (t >= 0 && t < 1024) {
      int tok = ipts[b * 1024 + t];
      v = *reinterpret_cast<const float4*>(emb + (size_t)tok * 64 + cc * 4);
    }
    ushort4 pv;
    pv.x = f2bf(v.x); pv.y = f2bf(v.y); pv.z = f2bf(v.z); pv.w = f2bf(v.w);
    *reinterpret_cast<ushort4*>(&xs[row][cc * 4]) = pv;
  }
  for (int c = tid; c < 128 * 24; c += 256) {   // stage B chunk
    int g = c / 24, cc = c % 24;
    *reinterpret_cast<ushort8*>(&wsb[g][cc * 8]) =
        *reinterpret_cast<const ushort8*>(CWb + (size_t)(g0 + g) * 192 + cc * 8);
  }
  __syncthreads();

  const int lane = tid & 63, wid = tid >> 6;
  const int wy = wid >> 1, wx = wid & 1;
  const int ln15 = lane & 15, lhi = lane >> 4;

  f32x4 acc[4][4];
#pragma unroll
  for (int i = 0; i < 4; ++i)
#pragma unroll
    for (int j = 0; j < 4; ++j) acc[i][j] = (f32x4){0.f, 0.f, 0.f, 0.f};

#pragma unroll
  for (int kk = 0; kk < 6; ++kk) {
    const int w = kk >> 1;                    // k = w*64 + e, never straddles w
    const int e0 = (kk & 1) * 32 + lhi * 8;   // e-offset of this lane's 8 elems
    const int k0 = kk * 32 + lhi * 8;
    bf16x8 a[4], bb[4];
#pragma unroll
    for (int i = 0; i < 4; ++i)
      a[i] = *reinterpret_cast<const bf16x8*>(&xs[wy * 64 + i * 16 + ln15 + w][e0]);
#pragma unroll
    for (int j = 0; j < 4; ++j)
      bb[j] = *reinterpret_cast<const bf16x8*>(&wsb[wx * 64 + j * 16 + ln15][k0]);
#pragma unroll
    for (int i = 0; i < 4; ++i)
#pragma unroll
      for (int j = 0; j < 4; ++j)
        acc[i][j] = __builtin_amdgcn_mfma_f32_16x16x32_bf16(a[i], bb[j], acc[i][j], 0, 0, 0);
  }

  float bias[4];
#pragma unroll
  for (int j = 0; j < 4; ++j) bias[j] = xbias[g0 + wx * 64 + j * 16 + ln15];

  unsigned short* outp = xp + (size_t)(b * 1024 + t0 + wy * 64) * 768 + g0 + wx * 64;
#pragma unroll
  for (int i = 0; i < 4; ++i)
#pragma unroll
    for (int r = 0; r < 4; ++r) {
      int m = i * 16 + lhi * 4 + r;           // C/D: col=lane&15, row=(lane>>4)*4+reg
#pragma unroll
      for (int j = 0; j < 4; ++j)
        outp[(size_t)m * 768 + j * 16 + ln15] = f2bf(acc[i][j][r] + bias[j]);
    }
}

// ---------------------------------------------------------------------------
// K2: GRU scan, one block (256 thr) per (batch, direction).
//     Thread owns rows {rbase, rbase+128, rbase+256} x k-half (half = tid&1);
//     weights as f16x2 in VGPRs, h as f16 in LDS (broadcast reads), dot via
//     v_dot2_f32_f16. k-half partner is the adjacent lane -> __shfl_xor(p,1).
__global__ __launch_bounds__(256) void k2_scan(
    const int* __restrict__ seqlen, const float* __restrict__ hidden,
    const float* __restrict__ w_hh_f, const float* __restrict__ b_hh_f,
    const float* __restrict__ w_hh_b, const float* __restrict__ b_hh_b,
    const unsigned short* __restrict__ xp, float* __restrict__ mot) {
  __shared__ __align__(16) unsigned short hh[128];  // h as f16
  __shared__ float ghb[384];
  const int tid = threadIdx.x;
  const int b = blockIdx.x & 63;
  const int dir = blockIdx.x >> 6;
  const float* whh = dir ? w_hh_b : w_hh_f;
  const float* bhh = dir ? b_hh_b : b_hh_f;
  const int half = tid & 1;
  const int rbase = tid >> 1;

  f16x2 wh[3][32];                    // 3 rows x 64 k-vals as f16 pairs (96 VGPR)
#pragma unroll
  for (int s = 0; s < 3; ++s) {
    const float4* rp4 =
        reinterpret_cast<const float4*>(whh + (size_t)(rbase + 128 * s) * 128 + half * 64);
#pragma unroll
    for (int c = 0; c < 16; ++c) {
      float4 v = rp4[c];
      f16x2 lo, hi;
      lo.x = (_Float16)v.x; lo.y = (_Float16)v.y;
      hi.x = (_Float16)v.z; hi.y = (_Float16)v.w;
      wh[s][2 * c] = lo; wh[s][2 * c + 1] = hi;
    }
  }

  const int len = seqlen[b];
  float h_reg = 0.f, acc = 0.f, bh0 = 0.f, bh1 = 0.f, bh2 = 0.f;
  if (tid < 128) {
    h_reg = hidden[(dir * 64 + b) * 128 + tid];
    hh[tid] = f2h_bits(h_reg);
    bh0 = bhh[tid]; bh1 = bhh[128 + tid]; bh2 = bhh[256 + tid];
  }
  const unsigned short* xpu = xp + (size_t)b * (1024 * 768) + dir * 384;
  unsigned short xr_r = 0, xz_r = 0, xn_r = 0;
  if (tid < 128) {
    int tr0 = dir ? (len - 1) : 0;
    const unsigned short* pp = xpu + (size_t)tr0 * 768 + tid;
    xr_r = pp[0]; xz_r = pp[128]; xn_r = pp[256];
  }
  __syncthreads();

  for (int t = 0; t < len; ++t) {
    ushort8 hv[8];
#pragma unroll
    for (int c = 0; c < 8; ++c)
      hv[c] = *reinterpret_cast<const ushort8*>(&hh[half * 64 + c * 8]);
    float p0 = 0.f, p1 = 0.f, p2 = 0.f;
#pragma unroll
    for (int c = 0; c < 8; ++c)
#pragma unroll
      for (int d = 0; d < 4; ++d) {
        f16x2 hp = us2h2(hv[c][2 * d], hv[c][2 * d + 1]);
        p0 = FDOT2(wh[0][c * 4 + d], hp, p0);
        p1 = FDOT2(wh[1][c * 4 + d], hp, p1);
        p2 = FDOT2(wh[2][c * 4 + d], hp, p2);
      }
    p0 += __shfl_xor(p0, 1);
    p1 += __shfl_xor(p1, 1);
    p2 += __shfl_xor(p2, 1);
    if (half == 0) {
      ghb[rbase] = p0; ghb[rbase + 128] = p1; ghb[rbase + 256] = p2;
    }
    __syncthreads();
    if (tid < 128) {
      float hr = ghb[tid], hz = ghb[128 + tid], hn = ghb[256 + tid];
      float xr = bf2f(xr_r), xz = bf2f(xz_r), xn = bf2f(xn_r);
      float r = 1.f / (1.f + __expf(-(xr + hr + bh0)));
      float z = 1.f / (1.f + __expf(-(xz + hz + bh1)));
      float narg = xn + r * (hn + bh2);
      float e2 = __expf(2.f * narg);
      float n = (e2 - 1.f) / (e2 + 1.f);
      float hnew = (1.f - z) * n + z * h_reg;
      acc += hnew;
      h_reg = hnew;
      hh[tid] = f2h_bits(hnew);
      if (t + 1 < len) {                     // prefetch next step's xp
        int trn = dir ? (len - 2 - t) : (t + 1);
        const unsigned short* pp = xpu + (size_t)trn * 768 + tid;
        xr_r = pp[0]; xz_r = pp[128]; xn_r = pp[256];
      }
    }
    __syncthreads();
  }
  if (tid < 128) mot[b * 256 + dir * 128 + tid] = acc / (float)len;
}

// ---------------------------------------------------------------------------
// K3: out[b] = sigmoid(dot(mot[b], lin_w) + lin_b)
__global__ void k3_final(const float* __restrict__ mot, const float* __restrict__ lin_w,
                         const float* __restrict__ lin_b, float* __restrict__ out) {
  int tid = threadIdx.x;
  int b = tid >> 2, part = tid & 3;
  float s = 0.f;
  for (int i = 0; i < 64; ++i) s += mot[b * 256 + part * 64 + i] * lin_w[part * 64 + i];
  s += __shfl_xor(s, 1);
  s += __shfl_xor(s, 2);
  if (part == 0) out[b] = 1.f / (1.f + __expf(-(s + lin_b[0])));
}

// ---------------------------------------------------------------------------
extern "C" void kernel_launch(void* const* d_in, const int* in_sizes, int n_in,
                              void* d_out, int out_size, void* d_ws, size_t ws_size,
                              hipStream_t stream) {
  const int*   ipts    = (const int*)d_in[0];
  const int*   seqlen  = (const int*)d_in[1];
  const float* hidden  = (const float*)d_in[2];
  const float* emb     = (const float*)d_in[3];
  const float* conv_w  = (const float*)d_in[4];
  const float* conv_b  = (const float*)d_in[5];
  const float* w_ih_f  = (const float*)d_in[6];
  const float* w_hh_f  = (const float*)d_in[7];
  const float* b_ih_f  = (const float*)d_in[8];
  const float* b_hh_f  = (const float*)d_in[9];
  const float* w_ih_b  = (const float*)d_in[10];
  const float* w_hh_b  = (const float*)d_in[11];
  const float* b_ih_b  = (const float*)d_in[12];
  const float* b_hh_b  = (const float*)d_in[13];
  const float* lin_w   = (const float*)d_in[14];
  const float* lin_b   = (const float*)d_in[15];

  char* ws = (char*)d_ws;
  unsigned short* CWb = (unsigned short*)(ws);         // 768*192*2 = 294,912 B
  float* xbias = (float*)(ws + 294912);                // 3,072 B
  float* mot   = (float*)(ws + 298240);                // 65,536 B
  unsigned short* xp = (unsigned short*)(ws + 1048576);  // 100,663,296 B (bf16)
  float* out = (float*)d_out;

  hipLaunchKernelGGL(k0_fuse, dim3(576), dim3(256), 0, stream,
                     conv_w, conv_b, w_ih_f, b_ih_f, w_ih_b, b_ih_b, CWb, xbias);
  hipLaunchKernelGGL(k1_gemm, dim3(3072), dim3(256), 0, stream,
                     ipts, emb, CWb, xbias, xp);
  hipLaunchKernelGGL(k2_scan, dim3(128), dim3(256), 0, stream,
                     seqlen, hidden, w_hh_f, b_hh_f, w_hh_b, b_hh_b, xp, mot);
  hipLaunchKernelGGL(k3_final, dim3(1), dim3(256), 0, stream, mot, lin_w, lin_b, out);
}

// Round 3
// 656.644 us; speedup vs baseline: 1.6524x; 1.0190x over previous
//
#include <hip/hip_runtime.h>

// V=50000, E=64, B=64, T=1024, F=128, H=128, WIN=3, PAD=1
// K = WIN*E = 192 fused reduction dim; G = 2*3H = 768 projection outputs

typedef __attribute__((ext_vector_type(8))) unsigned short ushort8;
typedef __attribute__((ext_vector_type(8))) short bf16x8;   // MFMA bf16 frag (guide §3)
typedef __attribute__((ext_vector_type(4))) float f32x4;
typedef _Float16 f16x2 __attribute__((ext_vector_type(2)));

__device__ __forceinline__ unsigned short f2bf(float f) {
  unsigned int u = __float_as_uint(f);
  u += 0x7fffu + ((u >> 16) & 1u);   // RNE
  return (unsigned short)(u >> 16);
}
__device__ __forceinline__ float bf2f(unsigned short us) {
  return __uint_as_float(((unsigned int)us) << 16);
}
__device__ __forceinline__ f16x2 us2h2(unsigned short a, unsigned short b) {
  unsigned int u = (unsigned int)a | ((unsigned int)b << 16);
  return __builtin_bit_cast(f16x2, u);
}
__device__ __forceinline__ unsigned short f2h_bits(float f) {
  _Float16 h = (_Float16)f;
  return __builtin_bit_cast(unsigned short, h);
}

#if __has_builtin(__builtin_amdgcn_fdot2)
#define FDOT2(a, b, c) __builtin_amdgcn_fdot2((a), (b), (c), false)
#else
#define FDOT2(a, b, c) ((float)(a).x * (float)(b).x + (float)(a).y * (float)(b).y + (c))
#endif

// ---------------------------------------------------------------------------
// K0: CWb[g][k] = bf16( sum_f Wih[g][f]*conv_w[f][k] ), xbias[g] = b_ih[g]+Wih[g]·conv_b
__global__ void k0_fuse(const float* __restrict__ conv_w, const float* __restrict__ conv_b,
                        const float* __restrict__ w_ih_f, const float* __restrict__ b_ih_f,
                        const float* __restrict__ w_ih_b, const float* __restrict__ b_ih_b,
                        unsigned short* __restrict__ CWb, float* __restrict__ xbias) {
  int flat = blockIdx.x * 256 + threadIdx.x;
  if (flat >= 768 * 192) return;
  int g = flat / 192, k = flat % 192;
  const float* wih = (g < 384) ? w_ih_f : w_ih_b;
  int gg = (g < 384) ? g : g - 384;
  float acc = 0.f;
  for (int f = 0; f < 128; ++f) acc += wih[gg * 128 + f] * conv_w[f * 192 + k];
  CWb[g * 192 + k] = f2bf(acc);
  if (k == 0) {
    const float* bih = (g < 384) ? b_ih_f : b_ih_b;
    float bb = bih[gg];
    for (int f = 0; f < 128; ++f) bb += wih[gg * 128 + f] * conv_b[f];
    xbias[g] = bb;
  }
}

// ---------------------------------------------------------------------------
// K1: xp[b][t][g] = bf16( xbias[g] + sum_k A[t][k]*CW[g][k] ) via MFMA bf16.
//     Block = 128t x 128g, K=192. 4 waves in 2x2, wave tile 64x64 (4x4 frags).
__global__ __launch_bounds__(256) void k1_gemm(const int* __restrict__ ipts,
                                               const float* __restrict__ emb,
                                               const unsigned short* __restrict__ CWb,
                                               const float* __restrict__ xbias,
                                               unsigned short* __restrict__ xp) {
  __shared__ __align__(16) unsigned short xs[130][72];    // bf16 emb rows, stride 144B
  __shared__ __align__(16) unsigned short wsb[128][200];  // bf16 CW chunk, stride 400B
  const int bid = blockIdx.x;
  const int gb = bid % 6, tb = bid / 6;
  const int b = tb >> 3, t0 = (tb & 7) << 7, g0 = gb << 7;
  const int tid = threadIdx.x;

  for (int c = tid; c < 130 * 16; c += 256) {   // stage A (gather + f32->bf16)
    int row = c >> 4, cc = c & 15;
    int t = t0 - 1 + row;
    float4 v = make_float4(0.f, 0.f, 0.f, 0.f);
    if (t >= 0 && t < 1024) {
      int tok = ipts[b * 1024 + t];
      v = *reinterpret_cast<const float4*>(emb + (size_t)tok * 64 + cc * 4);
    }
    ushort4 pv;
    pv.x = f2bf(v.x); pv.y = f2bf(v.y); pv.z = f2bf(v.z); pv.w = f2bf(v.w);
    *reinterpret_cast<ushort4*>(&xs[row][cc * 4]) = pv;
  }
  for (int c = tid; c < 128 * 24; c += 256) {   // stage B chunk
    int g = c / 24, cc = c % 24;
    *reinterpret_cast<ushort8*>(&wsb[g][cc * 8]) =
        *reinterpret_cast<const ushort8*>(CWb + (size_t)(g0 + g) * 192 + cc * 8);
  }
  __syncthreads();

  const int lane = tid & 63, wid = tid >> 6;
  const int wy = wid >> 1, wx = wid & 1;
  const int ln15 = lane & 15, lhi = lane >> 4;

  f32x4 acc[4][4];
#pragma unroll
  for (int i = 0; i < 4; ++i)
#pragma unroll
    for (int j = 0; j < 4; ++j) acc[i][j] = (f32x4){0.f, 0.f, 0.f, 0.f};

#pragma unroll
  for (int kk = 0; kk < 6; ++kk) {
    const int w = kk >> 1;                    // k = w*64 + e, never straddles w
    const int e0 = (kk & 1) * 32 + lhi * 8;
    const int k0 = kk * 32 + lhi * 8;
    bf16x8 a[4], bb[4];
#pragma unroll
    for (int i = 0; i < 4; ++i)
      a[i] = *reinterpret_cast<const bf16x8*>(&xs[wy * 64 + i * 16 + ln15 + w][e0]);
#pragma unroll
    for (int j = 0; j < 4; ++j)
      bb[j] = *reinterpret_cast<const bf16x8*>(&wsb[wx * 64 + j * 16 + ln15][k0]);
#pragma unroll
    for (int i = 0; i < 4; ++i)
#pragma unroll
      for (int j = 0; j < 4; ++j)
        acc[i][j] = __builtin_amdgcn_mfma_f32_16x16x32_bf16(a[i], bb[j], acc[i][j], 0, 0, 0);
  }

  float bias[4];
#pragma unroll
  for (int j = 0; j < 4; ++j) bias[j] = xbias[g0 + wx * 64 + j * 16 + ln15];

  unsigned short* outp = xp + (size_t)(b * 1024 + t0 + wy * 64) * 768 + g0 + wx * 64;
#pragma unroll
  for (int i = 0; i < 4; ++i)
#pragma unroll
    for (int r = 0; r < 4; ++r) {
      int m = i * 16 + lhi * 4 + r;           // C/D: col=lane&15, row=(lane>>4)*4+reg
#pragma unroll
      for (int j = 0; j < 4; ++j)
        outp[(size_t)m * 768 + j * 16 + ln15] = f2bf(acc[i][j][r] + bias[j]);
    }
}

// ---------------------------------------------------------------------------
// K2: GRU scan, one block (256 thr) per (batch, direction).
//     Thread pair (2j, 2j+1) owns output row j; each lane one k-half of the
//     3 gate dots (weights as f16x2 in VGPRs, h as f16 in double-buffered LDS,
//     v_dot2_f32_f16). shfl_xor(1) gives BOTH lanes the full sums -> both run
//     the gate combine redundantly with their own fp32 h_reg. No LDS reduce,
//     ONE barrier per step.
__global__ __launch_bounds__(256) void k2_scan(
    const int* __restrict__ seqlen, const float* __restrict__ hidden,
    const float* __restrict__ w_hh_f, const float* __restrict__ b_hh_f,
    const float* __restrict__ w_hh_b, const float* __restrict__ b_hh_b,
    const unsigned short* __restrict__ xp, float* __restrict__ mot) {
  __shared__ __align__(16) unsigned short hh[2][128];  // h as f16, double-buffered
  const int tid = threadIdx.x;
  const int b = blockIdx.x & 63;
  const int dir = blockIdx.x >> 6;
  const float* whh = dir ? w_hh_b : w_hh_f;
  const float* bhh = dir ? b_hh_b : b_hh_f;
  const int j = tid >> 1;      // output row 0..127
  const int half = tid & 1;    // k-half

  f16x2 wh[3][32];             // 3 gate rows x 64 k as f16 pairs (96 VGPR)
#pragma unroll
  for (int g = 0; g < 3; ++g) {
    const float4* rp4 =
        reinterpret_cast<const float4*>(whh + (size_t)(g * 128 + j) * 128 + half * 64);
#pragma unroll
    for (int c = 0; c < 16; ++c) {
      float4 v = rp4[c];
      f16x2 lo, hi;
      lo.x = (_Float16)v.x; lo.y = (_Float16)v.y;
      hi.x = (_Float16)v.z; hi.y = (_Float16)v.w;
      wh[g][2 * c] = lo; wh[g][2 * c + 1] = hi;
    }
  }

  const int len = seqlen[b];
  float h_reg = hidden[(dir * 64 + b) * 128 + j];
  if (half == 0) hh[0][j] = f2h_bits(h_reg);
  const float bh0 = bhh[j], bh1 = bhh[128 + j], bh2 = bhh[256 + j];

  const unsigned short* xpu = xp + (size_t)b * (1024 * 768) + dir * 384 + j;
  int tr0 = dir ? (len - 1) : 0;
  unsigned short xr_r = xpu[(size_t)tr0 * 768];
  unsigned short xz_r = xpu[(size_t)tr0 * 768 + 128];
  unsigned short xn_r = xpu[(size_t)tr0 * 768 + 256];
  float acc = 0.f;
  __syncthreads();

  for (int t = 0; t < len; ++t) {
    const int cur = t & 1;
    // h for this lane's k-half (broadcast reads, 2 addrs/wave)
    ushort8 hv[8];
#pragma unroll
    for (int c = 0; c < 8; ++c)
      hv[c] = *reinterpret_cast<const ushort8*>(&hh[cur][half * 64 + c * 8]);

    // prefetch next step's x projections (latency hides under the dots)
    unsigned short xr_n = 0, xz_n = 0, xn_n = 0;
    if (t + 1 < len) {
      int trn = dir ? (len - 2 - t) : (t + 1);
      const unsigned short* pp = xpu + (size_t)trn * 768;
      xr_n = pp[0]; xz_n = pp[128]; xn_n = pp[256];
    }

    float p0 = 0.f, p1 = 0.f, p2 = 0.f;
#pragma unroll
    for (int c = 0; c < 8; ++c)
#pragma unroll
      for (int d = 0; d < 4; ++d) {
        f16x2 hp = us2h2(hv[c][2 * d], hv[c][2 * d + 1]);
        p0 = FDOT2(wh[0][c * 4 + d], hp, p0);
        p1 = FDOT2(wh[1][c * 4 + d], hp, p1);
        p2 = FDOT2(wh[2][c * 4 + d], hp, p2);
      }
    p0 += __shfl_xor(p0, 1);
    p1 += __shfl_xor(p1, 1);
    p2 += __shfl_xor(p2, 1);

    // gate combine — redundantly in both lanes of the pair
    float xr = bf2f(xr_r), xz = bf2f(xz_r), xn = bf2f(xn_r);
    float r = 1.f / (1.f + __expf(-(xr + p0 + bh0)));
    float z = 1.f / (1.f + __expf(-(xz + p1 + bh1)));
    float narg = xn + r * (p2 + bh2);
    float e2 = __expf(2.f * narg);
    float n = (e2 - 1.f) / (e2 + 1.f);
    float hnew = (1.f - z) * n + z * h_reg;
    acc += hnew;
    h_reg = hnew;
    if (half == 0) hh[cur ^ 1][j] = f2h_bits(hnew);   // write NEXT buffer
    xr_r = xr_n; xz_r = xz_n; xn_r = xn_n;
    __syncthreads();   // orders: writes to next-buf visible; reads of cur done
  }
  if (half == 0) mot[b * 256 + dir * 128 + j] = acc / (float)len;
}

// ---------------------------------------------------------------------------
// K3: out[b] = sigmoid(dot(mot[b], lin_w) + lin_b)
__global__ void k3_final(const float* __restrict__ mot, const float* __restrict__ lin_w,
                         const float* __restrict__ lin_b, float* __restrict__ out) {
  int tid = threadIdx.x;
  int b = tid >> 2, part = tid & 3;
  float s = 0.f;
  for (int i = 0; i < 64; ++i) s += mot[b * 256 + part * 64 + i] * lin_w[part * 64 + i];
  s += __shfl_xor(s, 1);
  s += __shfl_xor(s, 2);
  if (part == 0) out[b] = 1.f / (1.f + __expf(-(s + lin_b[0])));
}

// ---------------------------------------------------------------------------
extern "C" void kernel_launch(void* const* d_in, const int* in_sizes, int n_in,
                              void* d_out, int out_size, void* d_ws, size_t ws_size,
                              hipStream_t stream) {
  const int*   ipts    = (const int*)d_in[0];
  const int*   seqlen  = (const int*)d_in[1];
  const float* hidden  = (const float*)d_in[2];
  const float* emb     = (const float*)d_in[3];
  const float* conv_w  = (const float*)d_in[4];
  const float* conv_b  = (const float*)d_in[5];
  const float* w_ih_f  = (const float*)d_in[6];
  const float* w_hh_f  = (const float*)d_in[7];
  const float* b_ih_f  = (const float*)d_in[8];
  const float* b_hh_f  = (const float*)d_in[9];
  const float* w_ih_b  = (const float*)d_in[10];
  const float* w_hh_b  = (const float*)d_in[11];
  const float* b_ih_b  = (const float*)d_in[12];
  const float* b_hh_b  = (const float*)d_in[13];
  const float* lin_w   = (const float*)d_in[14];
  const float* lin_b   = (const float*)d_in[15];

  char* ws = (char*)d_ws;
  unsigned short* CWb = (unsigned short*)(ws);           // 294,912 B
  float* xbias = (float*)(ws + 294912);                  // 3,072 B
  float* mot   = (float*)(ws + 298240);                  // 65,536 B
  unsigned short* xp = (unsigned short*)(ws + 1048576);  // 100,663,296 B (bf16)
  float* out = (float*)d_out;

  hipLaunchKernelGGL(k0_fuse, dim3(576), dim3(256), 0, stream,
                     conv_w, conv_b, w_ih_f, b_ih_f, w_ih_b, b_ih_b, CWb, xbias);
  hipLaunchKernelGGL(k1_gemm, dim3(3072), dim3(256), 0, stream,
                     ipts, emb, CWb, xbias, xp);
  hipLaunchKernelGGL(k2_scan, dim3(128), dim3(256), 0, stream,
                     seqlen, hidden, w_hh_f, b_hh_f, w_hh_b, b_hh_b, xp, mot);
  hipLaunchKernelGGL(k3_final, dim3(1), dim3(256), 0, stream, mot, lin_w, lin_b, out);
}

// Round 4
// 648.651 us; speedup vs baseline: 1.6728x; 1.0123x over previous
//
#include <hip/hip_runtime.h>

// V=50000, E=64, B=64, T=1024, F=128, H=128, WIN=3, PAD=1
// K = WIN*E = 192 fused reduction dim; G = 2*3H = 768 projection outputs

typedef __attribute__((ext_vector_type(8))) unsigned short ushort8;
typedef __attribute__((ext_vector_type(8))) short bf16x8;   // MFMA bf16 frag (guide §3)
typedef __attribute__((ext_vector_type(4))) float f32x4;
typedef _Float16 f16x2 __attribute__((ext_vector_type(2)));

__device__ __forceinline__ unsigned short f2bf(float f) {
  unsigned int u = __float_as_uint(f);
  u += 0x7fffu + ((u >> 16) & 1u);   // RNE
  return (unsigned short)(u >> 16);
}
__device__ __forceinline__ float bf2f(unsigned short us) {
  return __uint_as_float(((unsigned int)us) << 16);
}
__device__ __forceinline__ f16x2 us2h2(unsigned short a, unsigned short b) {
  unsigned int u = (unsigned int)a | ((unsigned int)b << 16);
  return __builtin_bit_cast(f16x2, u);
}
__device__ __forceinline__ unsigned short f2h_bits(float f) {
  _Float16 h = (_Float16)f;
  return __builtin_bit_cast(unsigned short, h);
}
__device__ __forceinline__ void gload_lds16(const void* g, void* l) {
  __builtin_amdgcn_global_load_lds((const __attribute__((address_space(1))) void*)g,
                                   (__attribute__((address_space(3))) void*)l, 16, 0, 0);
}

#if __has_builtin(__builtin_amdgcn_fdot2)
#define FDOT2(a, b, c) __builtin_amdgcn_fdot2((a), (b), (c), false)
#else
#define FDOT2(a, b, c) ((float)(a).x * (float)(b).x + (float)(a).y * (float)(b).y + (c))
#endif

// ---------------------------------------------------------------------------
// K0: CWb[g][k] = bf16( sum_f Wih[g][f]*conv_w[f][k] ), xbias[g] = b_ih[g]+Wih[g]·conv_b
__global__ void k0_fuse(const float* __restrict__ conv_w, const float* __restrict__ conv_b,
                        const float* __restrict__ w_ih_f, const float* __restrict__ b_ih_f,
                        const float* __restrict__ w_ih_b, const float* __restrict__ b_ih_b,
                        unsigned short* __restrict__ CWb, float* __restrict__ xbias) {
  int flat = blockIdx.x * 256 + threadIdx.x;
  if (flat >= 768 * 192) return;
  int g = flat / 192, k = flat % 192;
  const float* wih = (g < 384) ? w_ih_f : w_ih_b;
  int gg = (g < 384) ? g : g - 384;
  float acc = 0.f;
  for (int f = 0; f < 128; ++f) acc += wih[gg * 128 + f] * conv_w[f * 192 + k];
  CWb[g * 192 + k] = f2bf(acc);
  if (k == 0) {
    const float* bih = (g < 384) ? b_ih_f : b_ih_b;
    float bb = bih[gg];
    for (int f = 0; f < 128; ++f) bb += wih[gg * 128 + f] * conv_b[f];
    xbias[g] = bb;
  }
}

// ---------------------------------------------------------------------------
// K1: xp[b][t][g] = bf16( xbias[g] + sum_k A[t][k]*CW[g][k] ) via MFMA bf16.
//     Block = 128t x 128g, K=192. 4 waves in 2x2, wave tile 64x64 (4x4 frags).
__global__ __launch_bounds__(256) void k1_gemm(const int* __restrict__ ipts,
                                               const float* __restrict__ emb,
                                               const unsigned short* __restrict__ CWb,
                                               const float* __restrict__ xbias,
                                               unsigned short* __restrict__ xp) {
  __shared__ __align__(16) unsigned short xs[130][72];    // bf16 emb rows, stride 144B
  __shared__ __align__(16) unsigned short wsb[128][200];  // bf16 CW chunk, stride 400B
  const int bid = blockIdx.x;
  const int gb = bid % 6, tb = bid / 6;
  const int b = tb >> 3, t0 = (tb & 7) << 7, g0 = gb << 7;
  const int tid = threadIdx.x;

  for (int c = tid; c < 130 * 16; c += 256) {   // stage A (gather + f32->bf16)
    int row = c >> 4, cc = c & 15;
    int t = t0 - 1 + row;
    float4 v = make_float4(0.f, 0.f, 0.f, 0.f);
    if (t >= 0 && t < 1024) {
      int tok = ipts[b * 1024 + t];
      v = *reinterpret_cast<const float4*>(emb + (size_t)tok * 64 + cc * 4);
    }
    ushort4 pv;
    pv.x = f2bf(v.x); pv.y = f2bf(v.y); pv.z = f2bf(v.z); pv.w = f2bf(v.w);
    *reinterpret_cast<ushort4*>(&xs[row][cc * 4]) = pv;
  }
  for (int c = tid; c < 128 * 24; c += 256) {   // stage B chunk
    int g = c / 24, cc = c % 24;
    *reinterpret_cast<ushort8*>(&wsb[g][cc * 8]) =
        *reinterpret_cast<const ushort8*>(CWb + (size_t)(g0 + g) * 192 + cc * 8);
  }
  __syncthreads();

  const int lane = tid & 63, wid = tid >> 6;
  const int wy = wid >> 1, wx = wid & 1;
  const int ln15 = lane & 15, lhi = lane >> 4;

  f32x4 acc[4][4];
#pragma unroll
  for (int i = 0; i < 4; ++i)
#pragma unroll
    for (int j = 0; j < 4; ++j) acc[i][j] = (f32x4){0.f, 0.f, 0.f, 0.f};

#pragma unroll
  for (int kk = 0; kk < 6; ++kk) {
    const int w = kk >> 1;                    // k = w*64 + e, never straddles w
    const int e0 = (kk & 1) * 32 + lhi * 8;
    const int k0 = kk * 32 + lhi * 8;
    bf16x8 a[4], bb[4];
#pragma unroll
    for (int i = 0; i < 4; ++i)
      a[i] = *reinterpret_cast<const bf16x8*>(&xs[wy * 64 + i * 16 + ln15 + w][e0]);
#pragma unroll
    for (int j = 0; j < 4; ++j)
      bb[j] = *reinterpret_cast<const bf16x8*>(&wsb[wx * 64 + j * 16 + ln15][k0]);
#pragma unroll
    for (int i = 0; i < 4; ++i)
#pragma unroll
      for (int j = 0; j < 4; ++j)
        acc[i][j] = __builtin_amdgcn_mfma_f32_16x16x32_bf16(a[i], bb[j], acc[i][j], 0, 0, 0);
  }

  float bias[4];
#pragma unroll
  for (int j = 0; j < 4; ++j) bias[j] = xbias[g0 + wx * 64 + j * 16 + ln15];

  unsigned short* outp = xp + (size_t)(b * 1024 + t0 + wy * 64) * 768 + g0 + wx * 64;
#pragma unroll
  for (int i = 0; i < 4; ++i)
#pragma unroll
    for (int r = 0; r < 4; ++r) {
      int m = i * 16 + lhi * 4 + r;           // C/D: col=lane&15, row=(lane>>4)*4+reg
#pragma unroll
      for (int j = 0; j < 4; ++j)
        outp[(size_t)m * 768 + j * 16 + ln15] = f2bf(acc[i][j][r] + bias[j]);
    }
}

// ---------------------------------------------------------------------------
// K2: GRU scan, one block (256 thr = 4 waves) per (batch, direction).
//     Thread pair (2j,2j+1) owns row j, each lane one k-half; f16x2 weights in
//     VGPRs, h f16 in double-buffered LDS, v_dot2_f32_f16, shfl_xor(1) reduce,
//     redundant gate combine in both lanes.
//     xp staged in LDS tiles of 16 steps via global_load_lds (double-buffered):
//     loads for tile k+1 issued at step 16k, drained by a manual vmcnt(0) at
//     the tile-boundary barrier (15 steps of slack -> HBM latency fully hidden).
//     Per-step barrier is a raw s_barrier + lgkmcnt(0) (no vmcnt drain).
__global__ __launch_bounds__(256) void k2_scan(
    const int* __restrict__ seqlen, const float* __restrict__ hidden,
    const float* __restrict__ w_hh_f, const float* __restrict__ b_hh_f,
    const float* __restrict__ w_hh_b, const float* __restrict__ b_hh_b,
    const unsigned short* __restrict__ xp, float* __restrict__ mot) {
  __shared__ __align__(16) unsigned short hh[2][128];     // h as f16, double-buffered
  __shared__ __align__(16) unsigned short xt[2][16][384]; // xp tiles: 2 x 16 steps x 768B
  const int tid = threadIdx.x;
  const int b = blockIdx.x & 63;
  const int dir = blockIdx.x >> 6;
  const float* whh = dir ? w_hh_b : w_hh_f;
  const float* bhh = dir ? b_hh_b : b_hh_f;
  const int j = tid >> 1;      // output row 0..127
  const int half = tid & 1;    // k-half

  f16x2 wh[3][32];             // 3 gate rows x 64 k as f16 pairs (96 VGPR)
#pragma unroll
  for (int g = 0; g < 3; ++g) {
    const float4* rp4 =
        reinterpret_cast<const float4*>(whh + (size_t)(g * 128 + j) * 128 + half * 64);
#pragma unroll
    for (int c = 0; c < 16; ++c) {
      float4 v = rp4[c];
      f16x2 lo, hi;
      lo.x = (_Float16)v.x; lo.y = (_Float16)v.y;
      hi.x = (_Float16)v.z; hi.y = (_Float16)v.w;
      wh[g][2 * c] = lo; wh[g][2 * c + 1] = hi;
    }
  }

  const int len = seqlen[b];
  const unsigned short* xpb = xp + (size_t)b * (1024 * 768) + dir * 384;

  // prologue: stage tile 0 (steps 0..15; len >= 256 always covers it)
  {
    unsigned short* base = &xt[0][0][0];
#pragma unroll
    for (int i = 0; i < 3; ++i) {
      const int c = i * 256 + tid;          // 16B-chunk index 0..767
      const int st = c / 48, cc = c - st * 48;
      unsigned short* ldst = base + (size_t)(i * 256 + (tid & ~63)) * 8;
      const int row = dir ? (len - 1 - st) : st;
      gload_lds16(xpb + (size_t)row * 768 + cc * 8, ldst);
    }
  }

  float h_reg = hidden[(dir * 64 + b) * 128 + j];
  if (half == 0) hh[0][j] = f2h_bits(h_reg);
  const float bh0 = bhh[j], bh1 = bhh[128 + j], bh2 = bhh[256 + j];
  float acc = 0.f;
  __syncthreads();   // drains vmcnt (tile 0 ready) + lgkmcnt, full barrier

  for (int t = 0; t < len; ++t) {
    const int s = t & 15;
    const int buf = (t >> 4) & 1;
    const int cur = t & 1;

    // x-gate inputs for this step (ds reads; consumed ~250cyc later after dots)
    const unsigned short* xrow = &xt[buf][s][0];
    const unsigned short xr_r = xrow[j];
    const unsigned short xz_r = xrow[128 + j];
    const unsigned short xn_r = xrow[256 + j];

    // kick off next tile's loads into the other buffer (block-uniform branch)
    if (s == 0 && t + 16 < len) {
      const int ts = t + 16;
      unsigned short* base = &xt[buf ^ 1][0][0];
#pragma unroll
      for (int i = 0; i < 3; ++i) {
        const int c = i * 256 + tid;
        const int st = c / 48, cc = c - st * 48;
        const int at = ts + st;
        unsigned short* ldst = base + (size_t)(i * 256 + (tid & ~63)) * 8;
        if (at < len) {
          const int row = dir ? (len - 1 - at) : at;
          gload_lds16(xpb + (size_t)row * 768 + cc * 8, ldst);
        }
      }
    }

    // h for this lane's k-half (broadcast reads, 2 distinct addrs/wave)
    ushort8 hv[8];
#pragma unroll
    for (int c = 0; c < 8; ++c)
      hv[c] = *reinterpret_cast<const ushort8*>(&hh[cur][half * 64 + c * 8]);

    float p0 = 0.f, p1 = 0.f, p2 = 0.f;
#pragma unroll
    for (int c = 0; c < 8; ++c)
#pragma unroll
      for (int d = 0; d < 4; ++d) {
        f16x2 hp = us2h2(hv[c][2 * d], hv[c][2 * d + 1]);
        p0 = FDOT2(wh[0][c * 4 + d], hp, p0);
        p1 = FDOT2(wh[1][c * 4 + d], hp, p1);
        p2 = FDOT2(wh[2][c * 4 + d], hp, p2);
      }
    p0 += __shfl_xor(p0, 1);
    p1 += __shfl_xor(p1, 1);
    p2 += __shfl_xor(p2, 1);

    // gate combine — redundantly in both lanes of the pair
    float xr = bf2f(xr_r), xz = bf2f(xz_r), xn = bf2f(xn_r);
    float r = 1.f / (1.f + __expf(-(xr + p0 + bh0)));
    float z = 1.f / (1.f + __expf(-(xz + p1 + bh1)));
    float narg = xn + r * (p2 + bh2);
    float e2 = __expf(2.f * narg);
    float n = (e2 - 1.f) / (e2 + 1.f);
    float hnew = (1.f - z) * n + z * h_reg;
    acc += hnew;
    h_reg = hnew;
    if (half == 0) hh[cur ^ 1][j] = f2h_bits(hnew);   // publish h(t+1)

    // end-of-step: manual waits + raw barrier (no vmcnt drain except tile edge)
    if (((t + 1) & 15) == 0) asm volatile("s_waitcnt vmcnt(0)" ::: "memory");
    asm volatile("s_waitcnt lgkmcnt(0)" ::: "memory");
    __builtin_amdgcn_s_barrier();
    __builtin_amdgcn_sched_barrier(0);
  }
  if (half == 0) mot[b * 256 + dir * 128 + j] = acc / (float)len;
}

// ---------------------------------------------------------------------------
// K3: out[b] = sigmoid(dot(mot[b], lin_w) + lin_b)
__global__ void k3_final(const float* __restrict__ mot, const float* __restrict__ lin_w,
                         const float* __restrict__ lin_b, float* __restrict__ out) {
  int tid = threadIdx.x;
  int b = tid >> 2, part = tid & 3;
  float s = 0.f;
  for (int i = 0; i < 64; ++i) s += mot[b * 256 + part * 64 + i] * lin_w[part * 64 + i];
  s += __shfl_xor(s, 1);
  s += __shfl_xor(s, 2);
  if (part == 0) out[b] = 1.f / (1.f + __expf(-(s + lin_b[0])));
}

// ---------------------------------------------------------------------------
extern "C" void kernel_launch(void* const* d_in, const int* in_sizes, int n_in,
                              void* d_out, int out_size, void* d_ws, size_t ws_size,
                              hipStream_t stream) {
  const int*   ipts    = (const int*)d_in[0];
  const int*   seqlen  = (const int*)d_in[1];
  const float* hidden  = (const float*)d_in[2];
  const float* emb     = (const float*)d_in[3];
  const float* conv_w  = (const float*)d_in[4];
  const float* conv_b  = (const float*)d_in[5];
  const float* w_ih_f  = (const float*)d_in[6];
  const float* w_hh_f  = (const float*)d_in[7];
  const float* b_ih_f  = (const float*)d_in[8];
  const float* b_hh_f  = (const float*)d_in[9];
  const float* w_ih_b  = (const float*)d_in[10];
  const float* w_hh_b  = (const float*)d_in[11];
  const float* b_ih_b  = (const float*)d_in[12];
  const float* b_hh_b  = (const float*)d_in[13];
  const float* lin_w   = (const float*)d_in[14];
  const float* lin_b   = (const float*)d_in[15];

  char* ws = (char*)d_ws;
  unsigned short* CWb = (unsigned short*)(ws);           // 294,912 B
  float* xbias = (float*)(ws + 294912);                  // 3,072 B
  float* mot   = (float*)(ws + 298240);                  // 65,536 B
  unsigned short* xp = (unsigned short*)(ws + 1048576);  // 100,663,296 B (bf16)
  float* out = (float*)d_out;

  hipLaunchKernelGGL(k0_fuse, dim3(576), dim3(256), 0, stream,
                     conv_w, conv_b, w_ih_f, b_ih_f, w_ih_b, b_ih_b, CWb, xbias);
  hipLaunchKernelGGL(k1_gemm, dim3(3072), dim3(256), 0, stream,
                     ipts, emb, CWb, xbias, xp);
  hipLaunchKernelGGL(k2_scan, dim3(128), dim3(256), 0, stream,
                     seqlen, hidden, w_hh_f, b_hh_f, w_hh_b, b_hh_b, xp, mot);
  hipLaunchKernelGGL(k3_final, dim3(1), dim3(256), 0, stream, mot, lin_w, lin_b, out);
}